// Round 5
// baseline (1001.776 us; speedup 1.0000x reference)
//
#include <hip/hip_runtime.h>
#include <hip/hip_cooperative_groups.h>
#include <math.h>

namespace cg = cooperative_groups;

// Problem constants (fixed by setup_inputs)
#define B_   4
#define L_   512
#define D_   768
#define K_   10
#define P_   50
#define R_   1586          // 2*D + P
#define NP_  10642         // number of window pairs
#define MROWS 2048         // B_*L_
#define NPAD 1664          // 13*128, padded N for MFMA tiles
#define UVS  1600          // bf16 row stride for U/V/F (3200 B, 16B-aligned)

// out layout: pred [B,n] | emo_cau_pos [n,2] | h [B,n,R]  (all as float)
#define PRED_OFF 0
#define POS_OFF  (B_ * NP_)
#define H_OFF    (B_ * NP_ + NP_ * 2)

#define GRID_ 416           // 13 x 16 x 2 gemm tiles

typedef __attribute__((ext_vector_type(8))) short short8;    // 8 bf16 (MFMA A/B frag)
typedef __attribute__((ext_vector_type(4))) float floatx4;   // MFMA C/D frag

__device__ __forceinline__ unsigned short f2bf(float f) {
    union { float f; unsigned int u; } a; a.f = f;
    unsigned int u = a.u;
    return (unsigned short)((u + 0x7FFF + ((u >> 16) & 1)) >> 16);  // RNE
}
__device__ __forceinline__ float bf2f(unsigned short u) {
    union { unsigned int u; float f; } a; a.u = ((unsigned int)u) << 16;
    return a.f;
}

// ---- closed-form pair indexing ----
__device__ __forceinline__ int pair_offset(int i) {
    int h = i < K_ ? i : K_;
    int off = h * (K_ + 1) + (h * (h - 1)) / 2;
    if (i > K_) {
        int fullEnd = i < (L_ - K_) ? i : (L_ - K_);
        off += (fullEnd - K_) * (2 * K_ + 1);
        if (i > L_ - K_) {
            int t = i - (L_ - K_);
            int first = 2 * K_;
            int last = L_ + K_ - (i - 1);
            off += (first + last) * t / 2;
        }
    }
    return off;
}

#define CA_BLOCKS 1536      // MROWS*D_/1024
#define CW_BLOCKS 2496      // 24*52*2
#define PREP_JOBS (CA_BLOCKS + CW_BLOCKS + 21)

#define GLOAD_LDS16(g, l) __builtin_amdgcn_global_load_lds( \
    (const __attribute__((address_space(1))) void*)(g), \
    (__attribute__((address_space(3))) void*)(l), 16, 0, 0)

#define NC2 13   // ceil(793/64) float2-chunks per row

// ===================== fused: prep | gemm | epilogue =======================
__global__ __launch_bounds__(256, 2) void fused(
        const float* __restrict__ doc, const float* __restrict__ pos_emb,
        const float* __restrict__ W1, const float* __restrict__ b1,
        const float* __restrict__ W2, const float* __restrict__ b2,
        unsigned short* __restrict__ At, unsigned short* __restrict__ Wt,
        unsigned short* __restrict__ Fb, unsigned short* __restrict__ U,
        unsigned short* __restrict__ V, float* __restrict__ out) {
    __shared__ float tile[32][33];
    __shared__ float Es[P_];
    __shared__ unsigned short Alds[128 * 32];
    __shared__ unsigned short Blds[128 * 32];

    cg::grid_group grid = cg::this_grid();
    const int bid  = blockIdx.x;
    const int lane = threadIdx.x & 63;
    const int w    = threadIdx.x >> 6;

    // ---------------- phase 1: prep (R2 bodies, grid-strided) --------------
    for (int job = bid; job < PREP_JOBS; job += GRID_) {
        if (job < CA_BLOCKS) {                   // doc -> bf16 [2048][768]
            int idx = (job * 256 + threadIdx.x) * 4;
            float4 v = *(const float4*)(doc + idx);
            ushort4 o;
            o.x = f2bf(v.x); o.y = f2bf(v.y); o.z = f2bf(v.z); o.w = f2bf(v.w);
            *(ushort4*)(At + idx) = o;
        } else if (job < CA_BLOCKS + CW_BLOCKS) {    // W1 -> Wt[z][n][k] bf16
            int bb = job - CA_BLOCKS;
            int z = bb / 1248, rem = bb % 1248;
            int k0 = (rem % 24) * 32;
            int n0 = (rem / 24) * 32;
            int tx = threadIdx.x & 31, ty = threadIdx.x >> 5;
            #pragma unroll
            for (int r = 0; r < 4; ++r) {
                int k = k0 + ty + r * 8;
                int n = n0 + tx;
                tile[ty + r * 8][tx] = (n < R_) ? W1[(size_t)(z * D_ + k) * R_ + n] : 0.f;
            }
            __syncthreads();
            #pragma unroll
            for (int r = 0; r < 4; ++r) {
                int n = n0 + ty + r * 8;
                int k = k0 + tx;
                Wt[(size_t)z * NPAD * D_ + (size_t)n * D_ + k] = f2bf(tile[tx][ty + r * 8]);
            }
            __syncthreads();                     // WAR guard: tile reused next job
        } else {                                 // F = E @ W1[1536:,:] + b1
            int s = job - (CA_BLOCKS + CW_BLOCKS);
            if (threadIdx.x < P_) {
                float acc = 0.f;
                #pragma unroll
                for (int r = 0; r <= 2 * K_; ++r) {
                    float cnt = (float)(L_ - (r > K_ ? r - K_ : K_ - r));
                    float d = (float)(s - r);
                    acc += cnt * expf(-d * d) * pos_emb[r * P_ + threadIdx.x];
                }
                Es[threadIdx.x] = acc;
            }
            __syncthreads();
            for (int j = threadIdx.x; j < R_; j += 256) {
                float acc = b1[j];
                #pragma unroll 10
                for (int p = 0; p < P_; ++p)
                    acc += Es[p] * W1[(2 * D_ + p) * R_ + j];
                Fb[s * UVS + j] = f2bf(acc);
            }
            __syncthreads();                     // WAR guard on Es
        }
    }

    grid.sync();

    // ---------------- phase 2: gemm (R2 body, 1 tile per block) ------------
    {
        const int z   = bid / 208;
        const int rem = bid % 208;
        const int tileM = (rem / 13) * 128;
        const int tileN = (rem % 13) * 128;
        const unsigned short* Bt = Wt + (size_t)z * NPAD * D_;
        unsigned short* C = z ? V : U;

        const int wm = (w & 1) * 64, wn = (w >> 1) * 64;
        const int quad = lane >> 4, l16 = lane & 15;

        floatx4 acc[4][4] = {};

        for (int k0 = 0; k0 < D_; k0 += 32) {
            #pragma unroll
            for (int t = 0; t < 2; ++t) {
                int g = (t * 4 + w) * 64 + lane;
                int m = g >> 2, c = g & 3;
                GLOAD_LDS16(At + (size_t)(tileM + m) * D_ + k0 + c * 8,
                            Alds + (t * 4 + w) * 512);
                GLOAD_LDS16(Bt + (size_t)(tileN + m) * D_ + k0 + c * 8,
                            Blds + (t * 4 + w) * 512);
            }
            __syncthreads();
            short8 a[4], b[4];
            #pragma unroll
            for (int im = 0; im < 4; ++im)
                a[im] = *(const short8*)&Alds[(wm + im * 16 + l16) * 32 + quad * 8];
            #pragma unroll
            for (int in = 0; in < 4; ++in)
                b[in] = *(const short8*)&Blds[(wn + in * 16 + l16) * 32 + quad * 8];
            #pragma unroll
            for (int im = 0; im < 4; ++im)
                #pragma unroll
                for (int in = 0; in < 4; ++in)
                    acc[im][in] = __builtin_amdgcn_mfma_f32_16x16x32_bf16(
                        a[im], b[in], acc[im][in], 0, 0, 0);
            __syncthreads();
        }
        #pragma unroll
        for (int im = 0; im < 4; ++im) {
            #pragma unroll
            for (int in = 0; in < 4; ++in) {
                int col = tileN + wn + in * 16 + l16;
                if (col < R_) {
                    #pragma unroll
                    for (int r = 0; r < 4; ++r) {
                        int row = tileM + wm + im * 16 + quad * 4 + r;
                        C[(size_t)row * UVS + col] = f2bf(acc[im][in][r]);
                    }
                }
            }
        }
    }

    grid.sync();

    // ---------------- phase 3: epilogue (R2 body, grid-strided) ------------
    for (int job = bid; job < MROWS; job += GRID_) {
        const int b = job >> 9;                  // /L_
        const int i = job & (L_ - 1);

        const ushort2* u2  = (const ushort2*)(U + (size_t)(b * L_ + i) * UVS);
        const float2*  w2v = (const float2*)W2;

        float2 ur[NC2], wr[NC2];
        #pragma unroll
        for (int t = 0; t < NC2; ++t) {
            int c = lane + t * 64;
            if (c < R_ / 2) {
                ushort2 uu = u2[c];
                ur[t] = make_float2(bf2f(uu.x), bf2f(uu.y));
                wr[t] = w2v[c];
            }
        }

        const int base = i - K_ > 0 ? i - K_ : 0;
        const int poff = pair_offset(i);
        const float bias = b2[0];

        for (int dj = w; dj < 2 * K_ + 1; dj += 4) {
            int j = i - K_ + dj;
            if ((unsigned)j >= L_) continue;
            int p = poff + (j - base);
            const ushort2* v2 = (const ushort2*)(V + (size_t)(b * L_ + j) * UVS);
            const ushort2* f2 = (const ushort2*)(Fb + (size_t)dj * UVS);
            double* h2 = (double*)(out + H_OFF + (size_t)(b * NP_ + p) * R_);

            float acc = 0.f;
            #pragma unroll
            for (int t = 0; t < NC2; ++t) {
                int c = lane + t * 64;
                if (c < R_ / 2) {
                    ushort2 vv = v2[c], ff = f2[c];
                    float h0 = fmaxf(ur[t].x + bf2f(vv.x) + bf2f(ff.x), 0.f);
                    float h1 = fmaxf(ur[t].y + bf2f(vv.y) + bf2f(ff.y), 0.f);
                    union { float2 f; double d; } pk;
                    pk.f = make_float2(h0, h1);
                    __builtin_nontemporal_store(pk.d, h2 + c);
                    acc += h0 * wr[t].x + h1 * wr[t].y;
                }
            }
            #pragma unroll
            for (int off = 32; off; off >>= 1) acc += __shfl_down(acc, off, 64);
            if (lane == 0) {
                out[PRED_OFF + b * NP_ + p] = acc + bias;
                if (b == 0) {
                    out[POS_OFF + p * 2 + 0] = (float)(i + 1);
                    out[POS_OFF + p * 2 + 1] = (float)(j + 1);
                }
            }
        }
    }
}

extern "C" void kernel_launch(void* const* d_in, const int* in_sizes, int n_in,
                              void* d_out, int out_size, void* d_ws, size_t ws_size,
                              hipStream_t stream) {
    const float* doc     = (const float*)d_in[0];
    const float* pos_emb = (const float*)d_in[1];
    const float* W1      = (const float*)d_in[2];
    const float* b1      = (const float*)d_in[3];
    const float* W2      = (const float*)d_in[4];
    const float* b2      = (const float*)d_in[5];
    float* out = (float*)d_out;

    char* ws = (char*)d_ws;
    size_t off = 0;
    unsigned short* U  = (unsigned short*)(ws + off); off += (size_t)MROWS * UVS * 2;
    unsigned short* V  = (unsigned short*)(ws + off); off += (size_t)MROWS * UVS * 2;
    unsigned short* Fb = (unsigned short*)(ws + off); off += (size_t)21 * UVS * 2;
    off = (off + 255) & ~(size_t)255;
    unsigned short* At = (unsigned short*)(ws + off); off += (size_t)MROWS * D_ * 2;
    off = (off + 255) & ~(size_t)255;
    unsigned short* Wt = (unsigned short*)(ws + off);

    void* args[] = { (void*)&doc, (void*)&pos_emb, (void*)&W1, (void*)&b1,
                     (void*)&W2, (void*)&b2, (void*)&At, (void*)&Wt,
                     (void*)&Fb, (void*)&U, (void*)&V, (void*)&out };
    hipLaunchCooperativeKernel((const void*)fused, dim3(GRID_), dim3(256),
                               args, 0, stream);
}

// Round 6
// 352.597 us; speedup vs baseline: 2.8411x; 2.8411x over previous
//
#include <hip/hip_runtime.h>
#include <math.h>

// Problem constants (fixed by setup_inputs)
#define B_   4
#define L_   512
#define D_   768
#define K_   10
#define P_   50
#define R_   1586          // 2*D + P
#define NP_  10642         // number of window pairs
#define MROWS 2048         // B_*L_
#define NPAD 1664          // 13*128, padded N for MFMA tiles
#define UVS  1600          // bf16 row stride for U/V/F (3200 B, 16B-aligned)

// out layout: pred [B,n] | emo_cau_pos [n,2] | h [B,n,R]  (all as float)
#define PRED_OFF 0
#define POS_OFF  (B_ * NP_)
#define H_OFF    (B_ * NP_ + NP_ * 2)

typedef __attribute__((ext_vector_type(8))) short short8;    // 8 bf16 (MFMA A/B frag)
typedef __attribute__((ext_vector_type(4))) float floatx4;   // MFMA C/D frag

__device__ __forceinline__ unsigned short f2bf(float f) {
    union { float f; unsigned int u; } a; a.f = f;
    unsigned int u = a.u;
    return (unsigned short)((u + 0x7FFF + ((u >> 16) & 1)) >> 16);  // RNE
}
__device__ __forceinline__ float bf2f(unsigned short u) {
    union { unsigned int u; float f; } a; a.u = ((unsigned int)u) << 16;
    return a.f;
}

// ---- closed-form pair indexing ----
__device__ __forceinline__ int pair_offset(int i) {
    int h = i < K_ ? i : K_;
    int off = h * (K_ + 1) + (h * (h - 1)) / 2;
    if (i > K_) {
        int fullEnd = i < (L_ - K_) ? i : (L_ - K_);
        off += (fullEnd - K_) * (2 * K_ + 1);
        if (i > L_ - K_) {
            int t = i - (L_ - K_);
            int first = 2 * K_;
            int last = L_ + K_ - (i - 1);
            off += (first + last) * t / 2;
        }
    }
    return off;
}

// ================= merged prep: convert_A | convert_W | build_F =============
#define CA_BLOCKS 1536      // MROWS*D_/1024
#define CW_BLOCKS 2496      // 24*52*2
__global__ __launch_bounds__(256) void prep(
        const float* __restrict__ doc, const float* __restrict__ pos_emb,
        const float* __restrict__ W1, const float* __restrict__ b1,
        unsigned short* __restrict__ At, unsigned short* __restrict__ Wt,
        unsigned short* __restrict__ Fb) {
    __shared__ float tile[32][33];
    __shared__ float Es[P_];
    const int bid = blockIdx.x;

    if (bid < CA_BLOCKS) {                       // ---- doc -> bf16 [2048][768]
        int idx = (bid * 256 + threadIdx.x) * 4;
        float4 v = *(const float4*)(doc + idx);
        ushort4 o;
        o.x = f2bf(v.x); o.y = f2bf(v.y); o.z = f2bf(v.z); o.w = f2bf(v.w);
        *(ushort4*)(At + idx) = o;
        return;
    }
    if (bid < CA_BLOCKS + CW_BLOCKS) {           // ---- W1 -> Wt[z][n][k] bf16
        int bb = bid - CA_BLOCKS;
        int z = bb / 1248, rem = bb % 1248;
        int k0 = (rem % 24) * 32;
        int n0 = (rem / 24) * 32;
        int tx = threadIdx.x & 31, ty = threadIdx.x >> 5;
        #pragma unroll
        for (int r = 0; r < 4; ++r) {
            int k = k0 + ty + r * 8;
            int n = n0 + tx;
            tile[ty + r * 8][tx] = (n < R_) ? W1[(size_t)(z * D_ + k) * R_ + n] : 0.f;
        }
        __syncthreads();
        #pragma unroll
        for (int r = 0; r < 4; ++r) {
            int n = n0 + ty + r * 8;
            int k = k0 + tx;
            Wt[(size_t)z * NPAD * D_ + (size_t)n * D_ + k] = f2bf(tile[tx][ty + r * 8]);
        }
        return;
    }
    // ---- F[21][UVS] bf16 = E @ W1[1536:1586,:] + b1
    int s = bid - (CA_BLOCKS + CW_BLOCKS);
    if (threadIdx.x < P_) {
        float acc = 0.f;
        #pragma unroll
        for (int r = 0; r <= 2 * K_; ++r) {
            float cnt = (float)(L_ - (r > K_ ? r - K_ : K_ - r));
            float d = (float)(s - r);
            acc += cnt * expf(-d * d) * pos_emb[r * P_ + threadIdx.x];
        }
        Es[threadIdx.x] = acc;
    }
    __syncthreads();
    for (int j = threadIdx.x; j < R_; j += 256) {
        float acc = b1[j];
        #pragma unroll 10
        for (int p = 0; p < P_; ++p)
            acc += Es[p] * W1[(2 * D_ + p) * R_ + j];
        Fb[s * UVS + j] = f2bf(acc);
    }
}

// ===== MFMA GEMM: BK=64, dbuf + counted vmcnt + XOR swizzle + XCD locality
// C[z] = At(2048x768) @ Wt[z]^T -> bf16 [2048][UVS]
// XCD swizzle: 416 blocks = 8 XCDs x 52. XCD x owns sw in [52x, 52x+52):
// contiguous (z, tileN) slabs -> per-XCD L2 working set = At (3MB) + ~3.25
// B-slabs (0.65MB) < 4MB, so staging loads become L2 hits (T1).
#define GLOAD_LDS16(g, l) __builtin_amdgcn_global_load_lds( \
    (const __attribute__((address_space(1))) void*)(g), \
    (__attribute__((address_space(3))) void*)(l), 16, 0, 0)

__global__ __launch_bounds__(256) void gemm_mfma(
        const unsigned short* __restrict__ At,   // [2048][768] bf16
        const unsigned short* __restrict__ Wt,   // [2][1664][768] bf16 (B^T)
        unsigned short* __restrict__ U, unsigned short* __restrict__ V) {
    __shared__ unsigned short Alds[2][128 * 64];   // 2 x 16 KB
    __shared__ unsigned short Blds[2][128 * 64];

    // hardware round-robins consecutive blockIdx across XCDs: bid%8 = XCD
    const int sw  = (blockIdx.x & 7) * 52 + (blockIdx.x >> 3);   // bijective
    const int z   = sw / 208;
    const int rem = sw % 208;
    const int tileN = (rem / 16) * 128;
    const int tileM = (rem % 16) * 128;
    const unsigned short* Bt = Wt + (size_t)z * NPAD * D_;
    unsigned short* C = z ? V : U;

    const int lane = threadIdx.x & 63;
    const int w = threadIdx.x >> 6;
    const int wm = (w & 1) * 64, wn = (w >> 1) * 64;
    const int quad = lane >> 4, l16 = lane & 15;

    floatx4 acc[4][4] = {};

    // STAGE = full 128x64 A and B tiles: 16 chunks of 1KB (8 rows each),
    // 4 chunks per wave. Lane l covers row chunk*8 + (l>>3), phys slot l&7;
    // logical slot = (l&7) ^ (l>>3) (involution; row&7 == l>>3).
#define STAGE(buf, kk) do { \
        _Pragma("unroll") \
        for (int t = 0; t < 4; ++t) { \
            int chunk = t * 4 + w;               /* 0..15, wave-uniform */ \
            int r = chunk * 8 + (lane >> 3); \
            int sl = (lane & 7) ^ (lane >> 3);   /* pre-swizzled source slot */ \
            GLOAD_LDS16(At + (size_t)(tileM + r) * D_ + (kk) + sl * 8, \
                        &Alds[buf][chunk * 512]); \
            GLOAD_LDS16(Bt + (size_t)(tileN + r) * D_ + (kk) + sl * 8, \
                        &Blds[buf][chunk * 512]); \
        } } while (0)

    // K-step reading buf rb (compile-time), prefetching rb^1 with vmcnt(8):
    // waits only the PREVIOUS stage's 8 loads; fresh prefetch stays in flight.
#define KSTEP(rb, kk, dopf) do { \
        if (dopf) { \
            STAGE(rb ^ 1, (kk) + 64); \
            asm volatile("s_waitcnt vmcnt(8)" ::: "memory"); \
        } else { \
            asm volatile("s_waitcnt vmcnt(0)" ::: "memory"); \
        } \
        __builtin_amdgcn_s_barrier(); \
        __builtin_amdgcn_sched_barrier(0); \
        short8 a[4][2], b[4][2]; \
        _Pragma("unroll") \
        for (int im = 0; im < 4; ++im) \
            _Pragma("unroll") \
            for (int ks = 0; ks < 2; ++ks) \
                a[im][ks] = *(const short8*)&Alds[rb][ \
                    (wm + im * 16 + l16) * 64 + \
                    (((ks * 4 + quad) ^ (l16 & 7)) * 8)]; \
        _Pragma("unroll") \
        for (int in = 0; in < 4; ++in) \
            _Pragma("unroll") \
            for (int ks = 0; ks < 2; ++ks) \
                b[in][ks] = *(const short8*)&Blds[rb][ \
                    (wn + in * 16 + l16) * 64 + \
                    (((ks * 4 + quad) ^ (l16 & 7)) * 8)]; \
        _Pragma("unroll") \
        for (int im = 0; im < 4; ++im) \
            _Pragma("unroll") \
            for (int in = 0; in < 4; ++in) \
                _Pragma("unroll") \
                for (int ks = 0; ks < 2; ++ks) \
                    acc[im][in] = __builtin_amdgcn_mfma_f32_16x16x32_bf16( \
                        a[im][ks], b[in][ks], acc[im][in], 0, 0, 0); \
        __builtin_amdgcn_sched_barrier(0); \
        __builtin_amdgcn_s_barrier(); \
    } while (0)

    STAGE(0, 0);
    for (int k0 = 0; k0 < D_; k0 += 128) {       // 6 iters x 2 = 12 K-steps
        KSTEP(0, k0, true);
        KSTEP(1, k0 + 64, (k0 + 128) < D_);
    }
#undef KSTEP
#undef STAGE

    #pragma unroll
    for (int im = 0; im < 4; ++im) {
        #pragma unroll
        for (int in = 0; in < 4; ++in) {
            int col = tileN + wn + in * 16 + l16;
            if (col < R_) {
                #pragma unroll
                for (int r = 0; r < 4; ++r) {
                    int row = tileM + wm + im * 16 + quad * 4 + r;
                    C[(size_t)row * UVS + col] = f2bf(acc[im][in][r]);
                }
            }
        }
    }
}

// ==== epilogue: one BLOCK per (b,i) with XCD swizzle; wave w: dj = w,w+4,..
// XCD x owns sw in [256x, 256x+256) -> contiguous i-range per XCD: the 21
// V-rows each block reads are shared with in-XCD neighbors (L2-resident).
// Lane owns 8 consecutive elems; 16B short8 loads; normal float2 stores.
#define NG 4
__global__ __launch_bounds__(256) void epilogue(
        const unsigned short* __restrict__ U, const unsigned short* __restrict__ V,
        const unsigned short* __restrict__ Fb, const float* __restrict__ W2,
        const float* __restrict__ b2, float* __restrict__ out) {
    const int w    = threadIdx.x >> 6;
    const int lane = threadIdx.x & 63;
    const int sw   = (blockIdx.x & 7) * 256 + (blockIdx.x >> 3);  // bijective
    const int b    = sw >> 9;                 // /L_
    const int i    = sw & (L_ - 1);

    const unsigned short* urow = U + (size_t)(b * L_ + i) * UVS;

    float uf[NG][8], wf[NG][8];
    #pragma unroll
    for (int t = 0; t < NG; ++t) {
        int c = lane + t * 64;
        if (c < 198) {
            short8 uu = *(const short8*)(urow + 8 * c);
            float4 wa = *(const float4*)(W2 + 8 * c);
            float4 wb = *(const float4*)(W2 + 8 * c + 4);
            #pragma unroll
            for (int e = 0; e < 8; ++e) uf[t][e] = bf2f((unsigned short)uu[e]);
            wf[t][0] = wa.x; wf[t][1] = wa.y; wf[t][2] = wa.z; wf[t][3] = wa.w;
            wf[t][4] = wb.x; wf[t][5] = wb.y; wf[t][6] = wb.z; wf[t][7] = wb.w;
        } else if (c == 198) {                // elems 1584,1585
            ushort2 uu = *(const ushort2*)(urow + 1584);
            float2 wt = *(const float2*)(W2 + 1584);
            uf[t][0] = bf2f(uu.x); uf[t][1] = bf2f(uu.y);
            wf[t][0] = wt.x;       wf[t][1] = wt.y;
        }
    }

    const int base = i - K_ > 0 ? i - K_ : 0;
    const int poff = pair_offset(i);
    const float bias = b2[0];

    for (int dj = w; dj < 2 * K_ + 1; dj += 4) {
        int j = i - K_ + dj;
        if ((unsigned)j >= L_) continue;
        int p = poff + (j - base);
        const unsigned short* vrow = V + (size_t)(b * L_ + j) * UVS;
        const unsigned short* frow = Fb + (size_t)dj * UVS;
        float2* h2 = (float2*)(out + H_OFF + (size_t)(b * NP_ + p) * R_);

        float acc = 0.f;
        #pragma unroll
        for (int t = 0; t < NG; ++t) {
            int c = lane + t * 64;
            if (c < 198) {
                short8 vv = *(const short8*)(vrow + 8 * c);
                short8 ff = *(const short8*)(frow + 8 * c);
                float h[8];
                #pragma unroll
                for (int e = 0; e < 8; ++e) {
                    h[e] = fmaxf(uf[t][e] + bf2f((unsigned short)vv[e])
                                          + bf2f((unsigned short)ff[e]), 0.f);
                    acc += h[e] * wf[t][e];
                }
                #pragma unroll
                for (int q = 0; q < 4; ++q)
                    h2[4 * c + q] = make_float2(h[2 * q], h[2 * q + 1]);
            } else if (c == 198) {
                ushort2 vv = *(const ushort2*)(vrow + 1584);
                ushort2 ff = *(const ushort2*)(frow + 1584);
                float h0 = fmaxf(uf[t][0] + bf2f(vv.x) + bf2f(ff.x), 0.f);
                float h1 = fmaxf(uf[t][1] + bf2f(vv.y) + bf2f(ff.y), 0.f);
                h2[792] = make_float2(h0, h1);
                acc += h0 * wf[t][0] + h1 * wf[t][1];
            }
        }
        #pragma unroll
        for (int off = 32; off; off >>= 1) acc += __shfl_down(acc, off, 64);
        if (lane == 0) {
            out[PRED_OFF + b * NP_ + p] = acc + bias;
            if (b == 0) {
                out[POS_OFF + p * 2 + 0] = (float)(i + 1);
                out[POS_OFF + p * 2 + 1] = (float)(j + 1);
            }
        }
    }
}

extern "C" void kernel_launch(void* const* d_in, const int* in_sizes, int n_in,
                              void* d_out, int out_size, void* d_ws, size_t ws_size,
                              hipStream_t stream) {
    const float* doc     = (const float*)d_in[0];
    const float* pos_emb = (const float*)d_in[1];
    const float* W1      = (const float*)d_in[2];
    const float* b1      = (const float*)d_in[3];
    const float* W2      = (const float*)d_in[4];
    const float* b2      = (const float*)d_in[5];
    float* out = (float*)d_out;

    char* ws = (char*)d_ws;
    size_t off = 0;
    unsigned short* U  = (unsigned short*)(ws + off); off += (size_t)MROWS * UVS * 2;
    unsigned short* V  = (unsigned short*)(ws + off); off += (size_t)MROWS * UVS * 2;
    unsigned short* Fb = (unsigned short*)(ws + off); off += (size_t)21 * UVS * 2;
    off = (off + 255) & ~(size_t)255;
    unsigned short* At = (unsigned short*)(ws + off); off += (size_t)MROWS * D_ * 2;
    off = (off + 255) & ~(size_t)255;
    unsigned short* Wt = (unsigned short*)(ws + off);

    prep<<<CA_BLOCKS + CW_BLOCKS + 21, 256, 0, stream>>>(
        doc, pos_emb, W1, b1, At, Wt, Fb);
    gemm_mfma<<<416, 256, 0, stream>>>(At, Wt, U, V);
    epilogue<<<MROWS, 256, 0, stream>>>(U, V, Fb, W2, b2, out);
}

// Round 7
// 340.075 us; speedup vs baseline: 2.9457x; 1.0368x over previous
//
#include <hip/hip_runtime.h>
#include <math.h>

// Problem constants (fixed by setup_inputs)
#define B_   4
#define L_   512
#define D_   768
#define K_   10
#define P_   50
#define R_   1586          // 2*D + P
#define NP_  10642         // number of window pairs
#define MROWS 2048         // B_*L_
#define NPAD 1664          // 13*128, padded N for MFMA tiles
#define UVS  1600          // bf16 row stride for U/V/F (3200 B, 16B-aligned)

// out layout: pred [B,n] | emo_cau_pos [n,2] | h [B,n,R]  (all as float)
#define PRED_OFF 0
#define POS_OFF  (B_ * NP_)
#define H_OFF    (B_ * NP_ + NP_ * 2)

typedef __attribute__((ext_vector_type(8))) short short8;    // 8 bf16 (MFMA A/B frag)
typedef __attribute__((ext_vector_type(4))) float floatx4;   // MFMA C/D frag

__device__ __forceinline__ unsigned short f2bf(float f) {
    union { float f; unsigned int u; } a; a.f = f;
    unsigned int u = a.u;
    return (unsigned short)((u + 0x7FFF + ((u >> 16) & 1)) >> 16);  // RNE
}
__device__ __forceinline__ float bf2f(unsigned short u) {
    union { unsigned int u; float f; } a; a.u = ((unsigned int)u) << 16;
    return a.f;
}

// ---- closed-form pair indexing ----
__device__ __forceinline__ int pair_offset(int i) {
    int h = i < K_ ? i : K_;
    int off = h * (K_ + 1) + (h * (h - 1)) / 2;
    if (i > K_) {
        int fullEnd = i < (L_ - K_) ? i : (L_ - K_);
        off += (fullEnd - K_) * (2 * K_ + 1);
        if (i > L_ - K_) {
            int t = i - (L_ - K_);
            int first = 2 * K_;
            int last = L_ + K_ - (i - 1);
            off += (first + last) * t / 2;
        }
    }
    return off;
}

// ================= merged prep: convert_A | convert_W | build_F =============
#define CA_BLOCKS 1536      // MROWS*D_/1024
#define CW_BLOCKS 2496      // 24*52*2
__global__ __launch_bounds__(256) void prep(
        const float* __restrict__ doc, const float* __restrict__ pos_emb,
        const float* __restrict__ W1, const float* __restrict__ b1,
        unsigned short* __restrict__ At, unsigned short* __restrict__ Wt,
        unsigned short* __restrict__ Fb) {
    __shared__ float tile[32][33];
    __shared__ float Es[P_];
    const int bid = blockIdx.x;

    if (bid < CA_BLOCKS) {                       // ---- doc -> bf16 [2048][768]
        int idx = (bid * 256 + threadIdx.x) * 4;
        float4 v = *(const float4*)(doc + idx);
        ushort4 o;
        o.x = f2bf(v.x); o.y = f2bf(v.y); o.z = f2bf(v.z); o.w = f2bf(v.w);
        *(ushort4*)(At + idx) = o;
        return;
    }
    if (bid < CA_BLOCKS + CW_BLOCKS) {           // ---- W1 -> Wt[z][n][k] bf16
        int bb = bid - CA_BLOCKS;
        int z = bb / 1248, rem = bb % 1248;
        int k0 = (rem % 24) * 32;
        int n0 = (rem / 24) * 32;
        int tx = threadIdx.x & 31, ty = threadIdx.x >> 5;
        #pragma unroll
        for (int r = 0; r < 4; ++r) {
            int k = k0 + ty + r * 8;
            int n = n0 + tx;
            tile[ty + r * 8][tx] = (n < R_) ? W1[(size_t)(z * D_ + k) * R_ + n] : 0.f;
        }
        __syncthreads();
        #pragma unroll
        for (int r = 0; r < 4; ++r) {
            int n = n0 + ty + r * 8;
            int k = k0 + tx;
            Wt[(size_t)z * NPAD * D_ + (size_t)n * D_ + k] = f2bf(tile[tx][ty + r * 8]);
        }
        return;
    }
    // ---- F[21][UVS] bf16 = E @ W1[1536:1586,:] + b1
    int s = bid - (CA_BLOCKS + CW_BLOCKS);
    if (threadIdx.x < P_) {
        float acc = 0.f;
        #pragma unroll
        for (int r = 0; r <= 2 * K_; ++r) {
            float cnt = (float)(L_ - (r > K_ ? r - K_ : K_ - r));
            float d = (float)(s - r);
            acc += cnt * expf(-d * d) * pos_emb[r * P_ + threadIdx.x];
        }
        Es[threadIdx.x] = acc;
    }
    __syncthreads();
    for (int j = threadIdx.x; j < R_; j += 256) {
        float acc = b1[j];
        #pragma unroll 10
        for (int p = 0; p < P_; ++p)
            acc += Es[p] * W1[(2 * D_ + p) * R_ + j];
        Fb[s * UVS + j] = f2bf(acc);
    }
}

// ===== MFMA GEMM: BK=64, dbuf + counted vmcnt + XOR swizzle + XCD locality
// (unchanged from round 6 — best measured)
#define GLOAD_LDS16(g, l) __builtin_amdgcn_global_load_lds( \
    (const __attribute__((address_space(1))) void*)(g), \
    (__attribute__((address_space(3))) void*)(l), 16, 0, 0)

__global__ __launch_bounds__(256) void gemm_mfma(
        const unsigned short* __restrict__ At,   // [2048][768] bf16
        const unsigned short* __restrict__ Wt,   // [2][1664][768] bf16 (B^T)
        unsigned short* __restrict__ U, unsigned short* __restrict__ V) {
    __shared__ unsigned short Alds[2][128 * 64];   // 2 x 16 KB
    __shared__ unsigned short Blds[2][128 * 64];

    // hardware round-robins consecutive blockIdx across XCDs: bid%8 = XCD
    const int sw  = (blockIdx.x & 7) * 52 + (blockIdx.x >> 3);   // bijective
    const int z   = sw / 208;
    const int rem = sw % 208;
    const int tileN = (rem / 16) * 128;
    const int tileM = (rem % 16) * 128;
    const unsigned short* Bt = Wt + (size_t)z * NPAD * D_;
    unsigned short* C = z ? V : U;

    const int lane = threadIdx.x & 63;
    const int w = threadIdx.x >> 6;
    const int wm = (w & 1) * 64, wn = (w >> 1) * 64;
    const int quad = lane >> 4, l16 = lane & 15;

    floatx4 acc[4][4] = {};

#define STAGE(buf, kk) do { \
        _Pragma("unroll") \
        for (int t = 0; t < 4; ++t) { \
            int chunk = t * 4 + w;               /* 0..15, wave-uniform */ \
            int r = chunk * 8 + (lane >> 3); \
            int sl = (lane & 7) ^ (lane >> 3);   /* pre-swizzled source slot */ \
            GLOAD_LDS16(At + (size_t)(tileM + r) * D_ + (kk) + sl * 8, \
                        &Alds[buf][chunk * 512]); \
            GLOAD_LDS16(Bt + (size_t)(tileN + r) * D_ + (kk) + sl * 8, \
                        &Blds[buf][chunk * 512]); \
        } } while (0)

#define KSTEP(rb, kk, dopf) do { \
        if (dopf) { \
            STAGE(rb ^ 1, (kk) + 64); \
            asm volatile("s_waitcnt vmcnt(8)" ::: "memory"); \
        } else { \
            asm volatile("s_waitcnt vmcnt(0)" ::: "memory"); \
        } \
        __builtin_amdgcn_s_barrier(); \
        __builtin_amdgcn_sched_barrier(0); \
        short8 a[4][2], b[4][2]; \
        _Pragma("unroll") \
        for (int im = 0; im < 4; ++im) \
            _Pragma("unroll") \
            for (int ks = 0; ks < 2; ++ks) \
                a[im][ks] = *(const short8*)&Alds[rb][ \
                    (wm + im * 16 + l16) * 64 + \
                    (((ks * 4 + quad) ^ (l16 & 7)) * 8)]; \
        _Pragma("unroll") \
        for (int in = 0; in < 4; ++in) \
            _Pragma("unroll") \
            for (int ks = 0; ks < 2; ++ks) \
                b[in][ks] = *(const short8*)&Blds[rb][ \
                    (wn + in * 16 + l16) * 64 + \
                    (((ks * 4 + quad) ^ (l16 & 7)) * 8)]; \
        _Pragma("unroll") \
        for (int im = 0; im < 4; ++im) \
            _Pragma("unroll") \
            for (int in = 0; in < 4; ++in) \
                _Pragma("unroll") \
                for (int ks = 0; ks < 2; ++ks) \
                    acc[im][in] = __builtin_amdgcn_mfma_f32_16x16x32_bf16( \
                        a[im][ks], b[in][ks], acc[im][in], 0, 0, 0); \
        __builtin_amdgcn_sched_barrier(0); \
        __builtin_amdgcn_s_barrier(); \
    } while (0)

    STAGE(0, 0);
    for (int k0 = 0; k0 < D_; k0 += 128) {       // 6 iters x 2 = 12 K-steps
        KSTEP(0, k0, true);
        KSTEP(1, k0 + 64, (k0 + 128) < D_);
    }
#undef KSTEP
#undef STAGE

    #pragma unroll
    for (int im = 0; im < 4; ++im) {
        #pragma unroll
        for (int in = 0; in < 4; ++in) {
            int col = tileN + wn + in * 16 + l16;
            if (col < R_) {
                #pragma unroll
                for (int r = 0; r < 4; ++r) {
                    int row = tileM + wm + im * 16 + quad * 4 + r;
                    C[(size_t)row * UVS + col] = f2bf(acc[im][in][r]);
                }
            }
        }
    }
}

// ==== epilogue: one BLOCK per (b,i), XCD swizzle; wave w: dj = w, w+4, ...
// T14 async-split: dj+1's V-row loads issue (into the "next" register set)
// BEFORE dj's compute, so V latency hides under ~150 VALU cyc + store issue.
// Clamped j makes prefetch addresses always valid; compute/store guarded.
#define NG 4
__global__ __launch_bounds__(256) void epilogue(
        const unsigned short* __restrict__ U, const unsigned short* __restrict__ V,
        const unsigned short* __restrict__ Fb, const float* __restrict__ W2,
        const float* __restrict__ b2, float* __restrict__ out) {
    const int w    = threadIdx.x >> 6;
    const int lane = threadIdx.x & 63;
    const int sw   = (blockIdx.x & 7) * 256 + (blockIdx.x >> 3);  // bijective
    const int b    = sw >> 9;                 // /L_
    const int i    = sw & (L_ - 1);

    const unsigned short* vbase = V + (size_t)(b * L_) * UVS;
    const unsigned short* urow  = U + (size_t)(b * L_ + i) * UVS;

    // ---- prefetch first dj's V row (hides under U/W2 preload) ----
    int j0 = i - K_ + w;
    int jc0 = j0 < 0 ? 0 : (j0 > L_ - 1 ? L_ - 1 : j0);
    short8 nv0, nv1, nv2, nv3;
    {
        const unsigned short* vr = vbase + (size_t)jc0 * UVS;
        nv0 = *(const short8*)(vr + 8 * (lane));
        nv1 = *(const short8*)(vr + 8 * (lane + 64));
        nv2 = *(const short8*)(vr + 8 * (lane + 128));
        // group 3: c = lane+192; c<198 full, c==198 tail(2), else unused.
        int c3 = lane + 192;
        int off3 = c3 < 198 ? 8 * c3 : 1584;     // clamp to valid memory
        nv3 = *(const short8*)(vr + (off3 & ~7)); // 16B-aligned (off3 mult of 8)
    }

    float uf[NG][8], wf[NG][8];
    #pragma unroll
    for (int t = 0; t < NG; ++t) {
        int c = lane + t * 64;
        if (c < 198) {
            short8 uu = *(const short8*)(urow + 8 * c);
            float4 wa = *(const float4*)(W2 + 8 * c);
            float4 wb = *(const float4*)(W2 + 8 * c + 4);
            #pragma unroll
            for (int e = 0; e < 8; ++e) uf[t][e] = bf2f((unsigned short)uu[e]);
            wf[t][0] = wa.x; wf[t][1] = wa.y; wf[t][2] = wa.z; wf[t][3] = wa.w;
            wf[t][4] = wb.x; wf[t][5] = wb.y; wf[t][6] = wb.z; wf[t][7] = wb.w;
        } else if (c == 198) {                // elems 1584,1585
            ushort2 uu = *(const ushort2*)(urow + 1584);
            float2 wt = *(const float2*)(W2 + 1584);
            uf[t][0] = bf2f(uu.x); uf[t][1] = bf2f(uu.y);
            wf[t][0] = wt.x;       wf[t][1] = wt.y;
        }
    }

    const int base = i - K_ > 0 ? i - K_ : 0;
    const int poff = pair_offset(i);
    const float bias = b2[0];

    #pragma unroll 1
    for (int dj = w; dj < 2 * K_ + 1; dj += 4) {
        int j = i - K_ + dj;

        // rotate prefetched V into "current"
        short8 cv0 = nv0, cv1 = nv1, cv2 = nv2, cv3 = nv3;

        // issue next dj's V prefetch (wave-uniform branch)
        int djn = dj + 4;
        if (djn < 2 * K_ + 1) {
            int jn = i - K_ + djn;
            int jcn = jn < 0 ? 0 : (jn > L_ - 1 ? L_ - 1 : jn);
            const unsigned short* vr = vbase + (size_t)jcn * UVS;
            nv0 = *(const short8*)(vr + 8 * (lane));
            nv1 = *(const short8*)(vr + 8 * (lane + 64));
            nv2 = *(const short8*)(vr + 8 * (lane + 128));
            int c3 = lane + 192;
            int off3 = c3 < 198 ? 8 * c3 : 1584;
            nv3 = *(const short8*)(vr + (off3 & ~7));
        }

        if ((unsigned)j >= L_) continue;          // prefetch chain already advanced
        int p = poff + (j - base);
        const unsigned short* frow = Fb + (size_t)dj * UVS;
        float2* h2 = (float2*)(out + H_OFF + (size_t)(b * NP_ + p) * R_);

        float acc = 0.f;
        short8 cvs[NG] = { cv0, cv1, cv2, cv3 };  // static-indexed below
        #pragma unroll
        for (int t = 0; t < NG; ++t) {
            int c = lane + t * 64;
            if (c < 198) {
                short8 vv = cvs[t];
                short8 ff = *(const short8*)(frow + 8 * c);
                float h[8];
                #pragma unroll
                for (int e = 0; e < 8; ++e) {
                    h[e] = fmaxf(uf[t][e] + bf2f((unsigned short)vv[e])
                                          + bf2f((unsigned short)ff[e]), 0.f);
                    acc += h[e] * wf[t][e];
                }
                #pragma unroll
                for (int q = 0; q < 4; ++q)
                    h2[4 * c + q] = make_float2(h[2 * q], h[2 * q + 1]);
            } else if (c == 198) {
                short8 vv = cvs[t];               // holds elems 1584.. (tail)
                ushort2 ff = *(const ushort2*)(frow + 1584);
                float h0 = fmaxf(uf[t][0] + bf2f((unsigned short)vv[0]) + bf2f(ff.x), 0.f);
                float h1 = fmaxf(uf[t][1] + bf2f((unsigned short)vv[1]) + bf2f(ff.y), 0.f);
                h2[792] = make_float2(h0, h1);
                acc += h0 * wf[t][0] + h1 * wf[t][1];
            }
        }
        #pragma unroll
        for (int off = 32; off; off >>= 1) acc += __shfl_down(acc, off, 64);
        if (lane == 0) {
            out[PRED_OFF + b * NP_ + p] = acc + bias;
            if (b == 0) {
                out[POS_OFF + p * 2 + 0] = (float)(i + 1);
                out[POS_OFF + p * 2 + 1] = (float)(j + 1);
            }
        }
    }
}

extern "C" void kernel_launch(void* const* d_in, const int* in_sizes, int n_in,
                              void* d_out, int out_size, void* d_ws, size_t ws_size,
                              hipStream_t stream) {
    const float* doc     = (const float*)d_in[0];
    const float* pos_emb = (const float*)d_in[1];
    const float* W1      = (const float*)d_in[2];
    const float* b1      = (const float*)d_in[3];
    const float* W2      = (const float*)d_in[4];
    const float* b2      = (const float*)d_in[5];
    float* out = (float*)d_out;

    char* ws = (char*)d_ws;
    size_t off = 0;
    unsigned short* U  = (unsigned short*)(ws + off); off += (size_t)MROWS * UVS * 2;
    unsigned short* V  = (unsigned short*)(ws + off); off += (size_t)MROWS * UVS * 2;
    unsigned short* Fb = (unsigned short*)(ws + off); off += (size_t)21 * UVS * 2;
    off = (off + 255) & ~(size_t)255;
    unsigned short* At = (unsigned short*)(ws + off); off += (size_t)MROWS * D_ * 2;
    off = (off + 255) & ~(size_t)255;
    unsigned short* Wt = (unsigned short*)(ws + off);

    prep<<<CA_BLOCKS + CW_BLOCKS + 21, 256, 0, stream>>>(
        doc, pos_emb, W1, b1, At, Wt, Fb);
    gemm_mfma<<<416, 256, 0, stream>>>(At, Wt, U, V);
    epilogue<<<MROWS, 256, 0, stream>>>(U, V, Fb, W2, b2, out);
}